// Round 6
// baseline (968.832 us; speedup 1.0000x reference)
//
#include <hip/hip_runtime.h>
#include <cstddef>
#include <cstdint>

#define TMAX 512
#define HDIM 64

typedef _Float16 half2v __attribute__((ext_vector_type(2)));

__device__ __forceinline__ float fsig(float x) {
    x = fminf(fmaxf(x, -30.f), 30.f);
    float e = __expf(-x);
    return __builtin_amdgcn_rcpf(1.f + e);
}
__device__ __forceinline__ float ftanh(float x) {
    x = fminf(fmaxf(x, -15.f), 15.f);      // tanh(15)==1 in fp32; avoid inf/inf
    float e = __expf(2.f * x);
    return (e - 1.f) * __builtin_amdgcn_rcpf(e + 1.f);
}

#if __has_builtin(__builtin_amdgcn_fdot2)
__device__ __forceinline__ float dot2acc(half2v a, half2v b, float c) {
    return __builtin_amdgcn_fdot2(a, b, c, false);   // v_dot2_f32_f16
}
#else
__device__ __forceinline__ float dot2acc(half2v a, half2v b, float c) {
    return fmaf((float)a.y, (float)b.y, fmaf((float)a.x, (float)b.x, c));
}
#endif

// Block = 128 threads = 2 waves = ONE batch row.
//   wave A (wid=0): lane u owns gate rows u (i) and u+64 (f); owns c, does the
//                   cell update, h write, and the decoder head reduce.
//   wave B (wid=1): lane u owns gate rows u+128 (g) and u+192 (o); publishes
//                   tanh(g), sigmoid(o) through LDS.
//
// VGPR accounting (the whole game): 64 weight VGPRs + ~40 working ≈ 105.
// __launch_bounds__(128, 2): min 2 waves/EU -> 128-VGPR budget >= need.
// (Round 5's (128,4) capped the budget at 64 VGPRs -> wholesale scratch spill,
// WRITE_SIZE 2MB->24MB. Rounds 2-4 all had budget < footprint one way or
// another; this is the first config with budget > footprint.)
// At ~110 VGPRs the hardware still fits 4 waves/SIMD = the full 4096-wave grid.
__global__ __launch_bounds__(128, 2)
void lstm_2wave_kernel(const float* __restrict__ ctx_g,   // (B, T)
                       const float* __restrict__ Wih_e,   // (256,1)
                       const float* __restrict__ Whh_e,   // (256,64)
                       const float* __restrict__ bih_e,
                       const float* __restrict__ bhh_e,
                       const float* __restrict__ Wih_d,
                       const float* __restrict__ Whh_d,
                       const float* __restrict__ bih_d,
                       const float* __restrict__ bhh_d,
                       const float* __restrict__ Whead,   // (1,64)
                       const float* __restrict__ bhead,   // (1,)
                       float* __restrict__ out,           // (B, n_steps)
                       int T, int n_steps)
{
    __shared__ __align__(16) float    ctx_s[TMAX];
    __shared__ __align__(16) _Float16 h_s[HDIM];
    __shared__ __align__(16) float2   exch[HDIM];   // (tanh(g), sig(o)) per unit
    __shared__ float z_s;

    const int tid  = threadIdx.x;
    const int u    = tid & 63;          // hidden unit
    const int wid  = tid >> 6;          // 0 = wave A, 1 = wave B
    const int row  = blockIdx.x;        // batch row

    const float* ctxr = ctx_g + (size_t)row * T;
    for (int t = tid; t < T; t += 128) ctx_s[t] = ctxr[t];

    const int j0 = u + (wid << 7);      // A: u      | B: u+128
    const int j1 = j0 + 64;             // A: u+64   | B: u+192

    uint32_t w0[32], w1[32];            // fp16-packed W_hh rows (64 VGPRs)
    float wih0, wih1, b0, b1;

    // ---- encoder weights: convert once, pin in VGPRs ----
    {
        const float2* r0 = reinterpret_cast<const float2*>(Whh_e + (size_t)j0 * HDIM);
        const float2* r1 = reinterpret_cast<const float2*>(Whh_e + (size_t)j1 * HDIM);
        #pragma unroll
        for (int k = 0; k < 32; ++k) {
            float2 a = r0[k], b = r1[k];
            w0[k] = __builtin_bit_cast(uint32_t, half2v{(_Float16)a.x, (_Float16)a.y});
            w1[k] = __builtin_bit_cast(uint32_t, half2v{(_Float16)b.x, (_Float16)b.y});
        }
        wih0 = Wih_e[j0];  wih1 = Wih_e[j1];
        b0 = bih_e[j0] + bhh_e[j0];
        b1 = bih_e[j1] + bhh_e[j1];
    }
    #pragma unroll
    for (int k = 0; k < 32; ++k) asm volatile("" : "+v"(w0[k]), "+v"(w1[k]));
    asm volatile("" : "+v"(wih0), "+v"(wih1), "+v"(b0), "+v"(b1));

    float c = 0.f;
    if (wid == 0) h_s[u] = (_Float16)0.f;
    __syncthreads();

    // ---------------- encoder: T sequential steps ----------------
    for (int t = 0; t < T; ++t) {
        const float x = ctx_s[t];
        float a0A = fmaf(x, wih0, b0), a0B = 0.f;
        float a1A = fmaf(x, wih1, b1), a1B = 0.f;
        #pragma unroll
        for (int ch = 0; ch < 8; ++ch) {         // broadcast ds_read_b128
            uint4 hv = reinterpret_cast<const uint4*>(h_s)[ch];
            half2v hp[4];
            hp[0] = __builtin_bit_cast(half2v, hv.x);
            hp[1] = __builtin_bit_cast(half2v, hv.y);
            hp[2] = __builtin_bit_cast(half2v, hv.z);
            hp[3] = __builtin_bit_cast(half2v, hv.w);
            #pragma unroll
            for (int e = 0; e < 4; ++e) {
                const int k = ch * 4 + e;
                half2v wv0 = __builtin_bit_cast(half2v, w0[k]);
                half2v wv1 = __builtin_bit_cast(half2v, w1[k]);
                if (ch < 4) { a0A = dot2acc(wv0, hp[e], a0A); a1A = dot2acc(wv1, hp[e], a1A); }
                else        { a0B = dot2acc(wv0, hp[e], a0B); a1B = dot2acc(wv1, hp[e], a1B); }
            }
        }
        const float a0 = a0A + a0B;
        const float a1 = a1A + a1B;
        if (wid) {                                // B: publish tanh(g), sig(o)
            exch[u] = make_float2(ftanh(a0), fsig(a1));
        }
        __syncthreads();
        if (!wid) {                               // A: cell update
            const float ii = fsig(a0);
            const float ff = fsig(a1);
            const float2 go = exch[u];
            c = fmaf(ff, c, ii * go.x);
            h_s[u] = (_Float16)(go.y * ftanh(c));
        }
        __syncthreads();
    }

    // ---- decoder weights: convert once, pin ----
    {
        const float2* r0 = reinterpret_cast<const float2*>(Whh_d + (size_t)j0 * HDIM);
        const float2* r1 = reinterpret_cast<const float2*>(Whh_d + (size_t)j1 * HDIM);
        #pragma unroll
        for (int k = 0; k < 32; ++k) {
            float2 a = r0[k], b = r1[k];
            w0[k] = __builtin_bit_cast(uint32_t, half2v{(_Float16)a.x, (_Float16)a.y});
            w1[k] = __builtin_bit_cast(uint32_t, half2v{(_Float16)b.x, (_Float16)b.y});
        }
        wih0 = Wih_d[j0];  wih1 = Wih_d[j1];
        b0 = bih_d[j0] + bhh_d[j0];
        b1 = bih_d[j1] + bhh_d[j1];
    }
    #pragma unroll
    for (int k = 0; k < 32; ++k) asm volatile("" : "+v"(w0[k]), "+v"(w1[k]));
    asm volatile("" : "+v"(wih0), "+v"(wih1), "+v"(b0), "+v"(b1));

    const float wh = Whead[u];
    const float bh = bhead[0];
    float z = ctx_s[T - 1];                       // z0 = context[:, -1]

    // ---------------- decoder: n_steps sequential steps ----------------
    for (int s = 0; s < n_steps; ++s) {
        float a0A = fmaf(z, wih0, b0), a0B = 0.f;
        float a1A = fmaf(z, wih1, b1), a1B = 0.f;
        #pragma unroll
        for (int ch = 0; ch < 8; ++ch) {
            uint4 hv = reinterpret_cast<const uint4*>(h_s)[ch];
            half2v hp[4];
            hp[0] = __builtin_bit_cast(half2v, hv.x);
            hp[1] = __builtin_bit_cast(half2v, hv.y);
            hp[2] = __builtin_bit_cast(half2v, hv.z);
            hp[3] = __builtin_bit_cast(half2v, hv.w);
            #pragma unroll
            for (int e = 0; e < 4; ++e) {
                const int k = ch * 4 + e;
                half2v wv0 = __builtin_bit_cast(half2v, w0[k]);
                half2v wv1 = __builtin_bit_cast(half2v, w1[k]);
                if (ch < 4) { a0A = dot2acc(wv0, hp[e], a0A); a1A = dot2acc(wv1, hp[e], a1A); }
                else        { a0B = dot2acc(wv0, hp[e], a0B); a1B = dot2acc(wv1, hp[e], a1B); }
            }
        }
        const float a0 = a0A + a0B;
        const float a1 = a1A + a1B;
        if (wid) {
            exch[u] = make_float2(ftanh(a0), fsig(a1));
        }
        __syncthreads();
        if (!wid) {
            const float ii = fsig(a0);
            const float ff = fsig(a1);
            const float2 go = exch[u];
            c = fmaf(ff, c, ii * go.x);
            const float h = go.y * ftanh(c);
            h_s[u] = (_Float16)h;
            // head: z = sum_u h[u]*Whead[u] + b (fp32 butterfly on wave A)
            float p = h * wh;
            #pragma unroll
            for (int off = 32; off >= 1; off >>= 1)
                p += __shfl_xor(p, off);
            if (u == 0) {
                const float zn = p + bh;
                z_s = zn;
                out[(size_t)row * n_steps + s] = zn;
            }
        }
        __syncthreads();
        z = z_s;                                  // wave-uniform for both waves
    }
}

extern "C" void kernel_launch(void* const* d_in, const int* in_sizes, int n_in,
                              void* d_out, int out_size, void* d_ws, size_t ws_size,
                              hipStream_t stream)
{
    const float* ctx   = (const float*)d_in[0];
    const float* Wih_e = (const float*)d_in[1];
    const float* Whh_e = (const float*)d_in[2];
    const float* bih_e = (const float*)d_in[3];
    const float* bhh_e = (const float*)d_in[4];
    const float* Wih_d = (const float*)d_in[5];
    const float* Whh_d = (const float*)d_in[6];
    const float* bih_d = (const float*)d_in[7];
    const float* bhh_d = (const float*)d_in[8];
    const float* Whead = (const float*)d_in[9];
    const float* bhead = (const float*)d_in[10];
    float* out = (float*)d_out;

    const int B = 2048;                 // fixed by the harness setup
    const int T = in_sizes[0] / B;      // 512
    const int n_steps = out_size / B;   // 256

    lstm_2wave_kernel<<<dim3(B), dim3(128), 0, stream>>>(
        ctx, Wih_e, Whh_e, bih_e, bhh_e,
        Wih_d, Whh_d, bih_d, bhh_d,
        Whead, bhead, out, T, n_steps);
}

// Round 7
// 818.717 us; speedup vs baseline: 1.1834x; 1.1834x over previous
//
#include <hip/hip_runtime.h>
#include <cstddef>
#include <cstdint>

#define TMAX 512
#define HDIM 64

typedef _Float16 half2v __attribute__((ext_vector_type(2)));

__device__ __forceinline__ float fsig(float x) {
    x = fminf(fmaxf(x, -30.f), 30.f);
    float e = __expf(-x);
    return __builtin_amdgcn_rcpf(1.f + e);
}
__device__ __forceinline__ float ftanh(float x) {
    x = fminf(fmaxf(x, -15.f), 15.f);      // tanh(15)==1 in fp32; avoid inf/inf
    float e = __expf(2.f * x);
    return (e - 1.f) * __builtin_amdgcn_rcpf(e + 1.f);
}

#if __has_builtin(__builtin_amdgcn_fdot2)
__device__ __forceinline__ float dot2acc(half2v a, half2v b, float c) {
    return __builtin_amdgcn_fdot2(a, b, c, false);   // v_dot2_f32_f16
}
#else
__device__ __forceinline__ float dot2acc(half2v a, half2v b, float c) {
    return fmaf((float)a.y, (float)b.y, fmaf((float)a.x, (float)b.x, c));
}
#endif

// Force all 32 values of A into arch VGPRs at this program point.
// Placed at the TOP OF EVERY STEP ITERATION this makes the weights
// loop-carried (PHI) values with volatile-asm defs: not rematerializable,
// not AGPR-parkable without a per-iteration copy-storm RA won't pick.
#define PIN32(A) asm volatile("" \
  : "+v"(A[0]),  "+v"(A[1]),  "+v"(A[2]),  "+v"(A[3]),  \
    "+v"(A[4]),  "+v"(A[5]),  "+v"(A[6]),  "+v"(A[7]),  \
    "+v"(A[8]),  "+v"(A[9]),  "+v"(A[10]), "+v"(A[11]), \
    "+v"(A[12]), "+v"(A[13]), "+v"(A[14]), "+v"(A[15]), \
    "+v"(A[16]), "+v"(A[17]), "+v"(A[18]), "+v"(A[19]), \
    "+v"(A[20]), "+v"(A[21]), "+v"(A[22]), "+v"(A[23]), \
    "+v"(A[24]), "+v"(A[25]), "+v"(A[26]), "+v"(A[27]), \
    "+v"(A[28]), "+v"(A[29]), "+v"(A[30]), "+v"(A[31]))

// One wave (64 lanes) per batch row; lane u owns hidden unit u and computes
// gates u, u+64, u+128, u+192. Zero barriers, zero cross-wave traffic: h is
// exchanged via a 128-byte wave-private LDS buffer (broadcast reads, ordering
// by lgkmcnt within the wave).
// __launch_bounds__(64, 1): min 1 wave/EU -> full 512-VGPR budget. The grid
// is 2048 waves = 2 waves/SIMD device-wide, so occupancy beyond 2/SIMD has
// zero value; at ~180 VGPRs the HW still fits 2/SIMD.
__global__ __launch_bounds__(64, 1)
void lstm_wave_kernel(const float* __restrict__ ctx_g,   // (B, T)
                      const float* __restrict__ Wih_e,   // (256,1)
                      const float* __restrict__ Whh_e,   // (256,64)
                      const float* __restrict__ bih_e,
                      const float* __restrict__ bhh_e,
                      const float* __restrict__ Wih_d,
                      const float* __restrict__ Whh_d,
                      const float* __restrict__ bih_d,
                      const float* __restrict__ bhh_d,
                      const float* __restrict__ Whead,   // (1,64)
                      const float* __restrict__ bhead,   // (1,)
                      float* __restrict__ out,           // (B, n_steps)
                      int T, int n_steps)
{
    __shared__ __align__(16) float    ctx_s[TMAX];
    __shared__ __align__(16) _Float16 h_s[HDIM];

    const int lane = threadIdx.x;           // 0..63 == hidden unit
    const int row  = blockIdx.x;            // batch row

    const float* ctxr = ctx_g + (size_t)row * T;
    for (int t = lane; t < T; t += 64) ctx_s[t] = ctxr[t];

    uint32_t w[4][32];                       // fp16-packed W_hh rows: 128 VGPRs
    float    wih[4], bias[4];

    // ---- encoder weights: load + convert once ----
    #pragma unroll
    for (int g = 0; g < 4; ++g) {
        const int j = lane + (g << 6);
        const float2* wr = reinterpret_cast<const float2*>(Whh_e + (size_t)j * HDIM);
        #pragma unroll
        for (int k = 0; k < 32; ++k) {
            float2 wv = wr[k];
            w[g][k] = __builtin_bit_cast(uint32_t,
                          half2v{(_Float16)wv.x, (_Float16)wv.y});
        }
        wih[g]  = Wih_e[j];
        bias[g] = bih_e[j] + bhh_e[j];
    }

    float c = 0.f, h = 0.f;
    h_s[lane] = (_Float16)0.f;

    // ---------------- encoder: T sequential steps ----------------
    for (int t = 0; t < T; ++t) {
        PIN32(w[0]); PIN32(w[1]); PIN32(w[2]); PIN32(w[3]);
        const float x = ctx_s[t];
        float aA[4], aB[4];
        #pragma unroll
        for (int g = 0; g < 4; ++g) { aA[g] = fmaf(x, wih[g], bias[g]); aB[g] = 0.f; }
        #pragma unroll
        for (int ch = 0; ch < 8; ++ch) {     // 8 x ds_read_b128 (broadcast)
            uint4 hv = reinterpret_cast<const uint4*>(h_s)[ch];
            half2v hp[4];
            hp[0] = __builtin_bit_cast(half2v, hv.x);
            hp[1] = __builtin_bit_cast(half2v, hv.y);
            hp[2] = __builtin_bit_cast(half2v, hv.z);
            hp[3] = __builtin_bit_cast(half2v, hv.w);
            #pragma unroll
            for (int e = 0; e < 4; ++e) {
                const int k = ch * 4 + e;
                #pragma unroll
                for (int g = 0; g < 4; ++g) {
                    half2v wv = __builtin_bit_cast(half2v, w[g][k]);
                    if (ch < 4) aA[g] = dot2acc(wv, hp[e], aA[g]);
                    else        aB[g] = dot2acc(wv, hp[e], aB[g]);
                }
            }
        }
        const float ig = fsig(aA[0] + aB[0]);
        const float fg = fsig(aA[1] + aB[1]);
        const float gg = ftanh(aA[2] + aB[2]);
        const float og = fsig(aA[3] + aB[3]);
        c = fmaf(fg, c, ig * gg);
        h = og * ftanh(c);
        h_s[lane] = (_Float16)h;             // visible to the wave next step
    }

    // ---- decoder weights: load + convert once ----
    #pragma unroll
    for (int g = 0; g < 4; ++g) {
        const int j = lane + (g << 6);
        const float2* wr = reinterpret_cast<const float2*>(Whh_d + (size_t)j * HDIM);
        #pragma unroll
        for (int k = 0; k < 32; ++k) {
            float2 wv = wr[k];
            w[g][k] = __builtin_bit_cast(uint32_t,
                          half2v{(_Float16)wv.x, (_Float16)wv.y});
        }
        wih[g]  = Wih_d[j];
        bias[g] = bih_d[j] + bhh_d[j];
    }
    const float wh = Whead[lane];
    const float bh = bhead[0];
    float z = ctx_s[T - 1];                  // z0 = context[:, -1]
    float* outp = out + (size_t)row * n_steps;

    // ---------------- decoder: n_steps sequential steps ----------------
    for (int s = 0; s < n_steps; ++s) {
        PIN32(w[0]); PIN32(w[1]); PIN32(w[2]); PIN32(w[3]);
        float aA[4], aB[4];
        #pragma unroll
        for (int g = 0; g < 4; ++g) { aA[g] = fmaf(z, wih[g], bias[g]); aB[g] = 0.f; }
        #pragma unroll
        for (int ch = 0; ch < 8; ++ch) {
            uint4 hv = reinterpret_cast<const uint4*>(h_s)[ch];
            half2v hp[4];
            hp[0] = __builtin_bit_cast(half2v, hv.x);
            hp[1] = __builtin_bit_cast(half2v, hv.y);
            hp[2] = __builtin_bit_cast(half2v, hv.z);
            hp[3] = __builtin_bit_cast(half2v, hv.w);
            #pragma unroll
            for (int e = 0; e < 4; ++e) {
                const int k = ch * 4 + e;
                #pragma unroll
                for (int g = 0; g < 4; ++g) {
                    half2v wv = __builtin_bit_cast(half2v, w[g][k]);
                    if (ch < 4) aA[g] = dot2acc(wv, hp[e], aA[g]);
                    else        aB[g] = dot2acc(wv, hp[e], aB[g]);
                }
            }
        }
        const float ig = fsig(aA[0] + aB[0]);
        const float fg = fsig(aA[1] + aB[1]);
        const float gg = ftanh(aA[2] + aB[2]);
        const float og = fsig(aA[3] + aB[3]);
        c = fmaf(fg, c, ig * gg);
        h = og * ftanh(c);
        h_s[lane] = (_Float16)h;

        // head: z = sum_u h[u]*Whead[u] + b (fp32 butterfly; all lanes end
        // with the identical z, so it stays wave-uniform for the next step)
        float p = h * wh;
        #pragma unroll
        for (int off = 32; off >= 1; off >>= 1)
            p += __shfl_xor(p, off);
        z = p + bh;
        if (lane == 0) outp[s] = z;
    }
}

extern "C" void kernel_launch(void* const* d_in, const int* in_sizes, int n_in,
                              void* d_out, int out_size, void* d_ws, size_t ws_size,
                              hipStream_t stream)
{
    const float* ctx   = (const float*)d_in[0];
    const float* Wih_e = (const float*)d_in[1];
    const float* Whh_e = (const float*)d_in[2];
    const float* bih_e = (const float*)d_in[3];
    const float* bhh_e = (const float*)d_in[4];
    const float* Wih_d = (const float*)d_in[5];
    const float* Whh_d = (const float*)d_in[6];
    const float* bih_d = (const float*)d_in[7];
    const float* bhh_d = (const float*)d_in[8];
    const float* Whead = (const float*)d_in[9];
    const float* bhead = (const float*)d_in[10];
    float* out = (float*)d_out;

    const int B = 2048;                 // fixed by the harness setup
    const int T = in_sizes[0] / B;      // 512
    const int n_steps = out_size / B;   // 256

    lstm_wave_kernel<<<dim3(B), dim3(64), 0, stream>>>(
        ctx, Wih_e, Whh_e, bih_e, bhh_e,
        Wih_d, Whh_d, bih_d, bhh_d,
        Whead, bhead, out, T, n_steps);
}

// Round 8
// 617.921 us; speedup vs baseline: 1.5679x; 1.3250x over previous
//
#include <hip/hip_runtime.h>
#include <cstddef>
#include <cstdint>

#define TMAX 512
#define HDIM 64

typedef _Float16 half2v __attribute__((ext_vector_type(2)));

__device__ __forceinline__ float fsig(float x) {
    // overflow-safe without clamps: exp(-x)->inf => rcp->0 => 0; ->0 => 1
    float e = __expf(-x);
    return __builtin_amdgcn_rcpf(1.f + e);
}
__device__ __forceinline__ float ftanh(float x) {
    x = fminf(x, 15.f);                    // only upper clamp needed (e^2x inf)
    float e = __expf(2.f * x);
    return (e - 1.f) * __builtin_amdgcn_rcpf(e + 1.f);
}

#if __has_builtin(__builtin_amdgcn_fdot2)
__device__ __forceinline__ float dot2acc(half2v a, half2v b, float c) {
    return __builtin_amdgcn_fdot2(a, b, c, false);   // v_dot2_f32_f16
}
#else
__device__ __forceinline__ float dot2acc(half2v a, half2v b, float c) {
    return fmaf((float)a.y, (float)b.y, fmaf((float)a.x, (float)b.x, c));
}
#endif

// ---------------------------------------------------------------------------
// Setup kernel: pre-pack W_hh (enc & dec) to fp16 pairs in d_ws, in the exact
// order the main loop consumes them, so the per-step weight reload is 32
// coalesced dwordx4 loads and ZERO convert instructions.
//
// Output u32 index: o = m*8192 + ((g*8 + ch)*64 + u)*4 + e
//   m: 0=enc 1=dec | g: gate 0..3 | ch: k-chunk 0..7 | u: lane | e: pair 0..3
//   word = pack_f16(W[g*64+u][ch*8+e*2], W[g*64+u][ch*8+e*2+1])
// Main-loop load i (= g*8+ch): lanes read consecutive uint4 at ws4[i*64+lane].
// ---------------------------------------------------------------------------
__global__ void pack_weights_kernel(const float* __restrict__ Whh_e,
                                    const float* __restrict__ Whh_d,
                                    uint32_t* __restrict__ ws)
{
    const int o  = blockIdx.x * 256 + threadIdx.x;    // 0..16383
    const int m  = o >> 13;
    const int p  = o & 8191;
    const int g  = p >> 11;
    const int ch = (p >> 8) & 7;
    const int u  = (p >> 2) & 63;
    const int e  = p & 3;
    const float* W = m ? Whh_d : Whh_e;
    const int j   = (g << 6) + u;
    const int col = ch * 8 + e * 2;
    const float a = W[j * 64 + col];
    const float b = W[j * 64 + col + 1];
    ws[o] = __builtin_bit_cast(uint32_t, half2v{(_Float16)a, (_Float16)b});
}

// One wave (64 lanes) per batch row; lane u owns hidden unit u and computes
// gates u, u+64, u+128, u+192. Zero barriers: h is exchanged via a 128-byte
// wave-private LDS buffer (broadcast reads; wave-internal ordering by lgkmcnt).
// Weights are re-read every step from the pre-packed d_ws image — 32 coalesced
// dwordx4 per step, L1-resident (4 KB distinct per CU), no converts. This is
// the dataflow the register allocator *wants* (rounds 2-7: it refuses cheap
// residency of a 128-VGPR invariant array), made cheap instead of fought.
__global__ __launch_bounds__(64, 2)
void lstm_wave_kernel(const float* __restrict__ ctx_g,   // (B, T)
                      const float* __restrict__ Wih_e,   // (256,1)
                      const float* __restrict__ bih_e,
                      const float* __restrict__ bhh_e,
                      const float* __restrict__ Wih_d,
                      const float* __restrict__ bih_d,
                      const float* __restrict__ bhh_d,
                      const float* __restrict__ Whead,   // (1,64)
                      const float* __restrict__ bhead,   // (1,)
                      const uint4* __restrict__ wpack,   // packed W_hh enc|dec
                      float* __restrict__ out,           // (B, n_steps)
                      int T, int n_steps)
{
    __shared__ __align__(16) float    ctx_s[TMAX];
    __shared__ __align__(16) _Float16 h_s[HDIM];

    const int lane = threadIdx.x;           // 0..63 == hidden unit
    const int row  = blockIdx.x;            // batch row

    const float* ctxr = ctx_g + (size_t)row * T;
    for (int t = lane; t < T; t += 64) ctx_s[t] = ctxr[t];

    float wih[4], bias[4];
    #pragma unroll
    for (int g = 0; g < 4; ++g) {
        const int j = lane + (g << 6);
        wih[g]  = Wih_e[j];
        bias[g] = bih_e[j] + bhh_e[j];
    }

    float c = 0.f, h = 0.f;
    h_s[lane] = (_Float16)0.f;
    const uint4* wp = wpack;                // encoder image

    // ---------------- encoder: T sequential steps ----------------
    for (int t = 0; t < T; ++t) {
        uint4 wv[32];
        #pragma unroll
        for (int i = 0; i < 32; ++i) wv[i] = wp[(i << 6) | lane];
        const float x = ctx_s[t];
        float aA[4], aB[4];
        #pragma unroll
        for (int g = 0; g < 4; ++g) { aA[g] = fmaf(x, wih[g], bias[g]); aB[g] = 0.f; }
        #pragma unroll
        for (int ch = 0; ch < 8; ++ch) {     // 8 x ds_read_b128 (broadcast)
            uint4 hv = reinterpret_cast<const uint4*>(h_s)[ch];
            half2v hp[4];
            hp[0] = __builtin_bit_cast(half2v, hv.x);
            hp[1] = __builtin_bit_cast(half2v, hv.y);
            hp[2] = __builtin_bit_cast(half2v, hv.z);
            hp[3] = __builtin_bit_cast(half2v, hv.w);
            #pragma unroll
            for (int g = 0; g < 4; ++g) {
                const uint32_t* wc = reinterpret_cast<const uint32_t*>(&wv[g * 8 + ch]);
                #pragma unroll
                for (int e = 0; e < 4; ++e) {
                    half2v wvh = __builtin_bit_cast(half2v, wc[e]);
                    if (ch < 4) aA[g] = dot2acc(wvh, hp[e], aA[g]);
                    else        aB[g] = dot2acc(wvh, hp[e], aB[g]);
                }
            }
        }
        const float ig = fsig(aA[0] + aB[0]);
        const float fg = fsig(aA[1] + aB[1]);
        const float gg = ftanh(aA[2] + aB[2]);
        const float og = fsig(aA[3] + aB[3]);
        c = fmaf(fg, c, ig * gg);
        h = og * ftanh(c);
        h_s[lane] = (_Float16)h;             // visible to the wave next step
    }

    // ---------------- decoder setup ----------------
    #pragma unroll
    for (int g = 0; g < 4; ++g) {
        const int j = lane + (g << 6);
        wih[g]  = Wih_d[j];
        bias[g] = bih_d[j] + bhh_d[j];
    }
    const float wh = Whead[lane];
    const float bh = bhead[0];
    float z = ctx_s[T - 1];                  // z0 = context[:, -1]
    float* outp = out + (size_t)row * n_steps;
    wp = wpack + 2048;                       // decoder image (8192 u32 offset)

    // ---------------- decoder: n_steps sequential steps ----------------
    for (int s = 0; s < n_steps; ++s) {
        uint4 wv[32];
        #pragma unroll
        for (int i = 0; i < 32; ++i) wv[i] = wp[(i << 6) | lane];
        float aA[4], aB[4];
        #pragma unroll
        for (int g = 0; g < 4; ++g) { aA[g] = fmaf(z, wih[g], bias[g]); aB[g] = 0.f; }
        #pragma unroll
        for (int ch = 0; ch < 8; ++ch) {
            uint4 hv = reinterpret_cast<const uint4*>(h_s)[ch];
            half2v hp[4];
            hp[0] = __builtin_bit_cast(half2v, hv.x);
            hp[1] = __builtin_bit_cast(half2v, hv.y);
            hp[2] = __builtin_bit_cast(half2v, hv.z);
            hp[3] = __builtin_bit_cast(half2v, hv.w);
            #pragma unroll
            for (int g = 0; g < 4; ++g) {
                const uint32_t* wc = reinterpret_cast<const uint32_t*>(&wv[g * 8 + ch]);
                #pragma unroll
                for (int e = 0; e < 4; ++e) {
                    half2v wvh = __builtin_bit_cast(half2v, wc[e]);
                    if (ch < 4) aA[g] = dot2acc(wvh, hp[e], aA[g]);
                    else        aB[g] = dot2acc(wvh, hp[e], aB[g]);
                }
            }
        }
        const float ig = fsig(aA[0] + aB[0]);
        const float fg = fsig(aA[1] + aB[1]);
        const float gg = ftanh(aA[2] + aB[2]);
        const float og = fsig(aA[3] + aB[3]);
        c = fmaf(fg, c, ig * gg);
        h = og * ftanh(c);
        h_s[lane] = (_Float16)h;

        // head: z = sum_u h[u]*Whead[u] + b (fp32 butterfly; all lanes end
        // with the identical z, so it stays wave-uniform for the next step)
        float p = h * wh;
        #pragma unroll
        for (int off = 32; off >= 1; off >>= 1)
            p += __shfl_xor(p, off);
        z = p + bh;
        if (lane == 0) outp[s] = z;
    }
}

extern "C" void kernel_launch(void* const* d_in, const int* in_sizes, int n_in,
                              void* d_out, int out_size, void* d_ws, size_t ws_size,
                              hipStream_t stream)
{
    const float* ctx   = (const float*)d_in[0];
    const float* Wih_e = (const float*)d_in[1];
    const float* Whh_e = (const float*)d_in[2];
    const float* bih_e = (const float*)d_in[3];
    const float* bhh_e = (const float*)d_in[4];
    const float* Wih_d = (const float*)d_in[5];
    const float* Whh_d = (const float*)d_in[6];
    const float* bih_d = (const float*)d_in[7];
    const float* bhh_d = (const float*)d_in[8];
    const float* Whead = (const float*)d_in[9];
    const float* bhead = (const float*)d_in[10];
    float* out = (float*)d_out;

    const int B = 2048;                 // fixed by the harness setup
    const int T = in_sizes[0] / B;      // 512
    const int n_steps = out_size / B;   // 256

    // pack both W_hh matrices to fp16 pairs in d_ws (64 KB used)
    pack_weights_kernel<<<dim3(64), dim3(256), 0, stream>>>(
        Whh_e, Whh_d, (uint32_t*)d_ws);

    lstm_wave_kernel<<<dim3(B), dim3(64), 0, stream>>>(
        ctx, Wih_e, bih_e, bhh_e,
        Wih_d, bih_d, bhh_d,
        Whead, bhead, (const uint4*)d_ws, out, T, n_steps);
}